// Round 1
// baseline (740.173 us; speedup 1.0000x reference)
//
#include <hip/hip_runtime.h>

#define NA    50000
#define NFEAT 512
#define HID   512
#define NC    128
#define AH    64
#define NE    800000
#define NHOP  4

typedef __bf16 bf16x8 __attribute__((ext_vector_type(8)));
typedef float  f32x4  __attribute__((ext_vector_type(4)));

__device__ __forceinline__ unsigned short f2bf(float f){
  union { float f; unsigned u; } a; a.f = f;
  return (unsigned short)((a.u + 0x7fffu + ((a.u >> 16) & 1u)) >> 16);  // RNE
}
__device__ __forceinline__ float bf2f(unsigned short h){
  union { unsigned u; float f; } a; a.u = ((unsigned)h) << 16;
  return a.f;
}
__device__ __forceinline__ float tanh_fast(float x){
  x = fminf(15.f, fmaxf(-15.f, x));
  float e = __expf(2.f * x);
  return (e - 1.f) / (e + 1.f);
}

__device__ __forceinline__ void g2l16(const void* g, void* l){
  __builtin_amdgcn_global_load_lds(
      (const __attribute__((address_space(1))) void*)g,
      (__attribute__((address_space(3))) void*)l, 16, 0, 0);
}

// ---------------- casts / transposes ----------------

__global__ void cast_x_kernel(const float* __restrict__ in, unsigned short* __restrict__ out, int n4){
  int i = blockIdx.x * 256 + threadIdx.x;
  if (i >= n4) return;
  float4 v = reinterpret_cast<const float4*>(in)[i];
  ushort4 o; o.x = f2bf(v.x); o.y = f2bf(v.y); o.z = f2bf(v.z); o.w = f2bf(v.w);
  reinterpret_cast<ushort4*>(out)[i] = o;
}

// in [R][N] f32 -> out [N][R] bf16 (i.e. out = in^T)
__global__ void transpose_cast_kernel(const float* __restrict__ in, unsigned short* __restrict__ out,
                                      int R, int N){
  int i = blockIdx.x * 256 + threadIdx.x;
  if (i >= R * N) return;
  int n = i / R, k = i - n * R;
  out[i] = f2bf(in[(size_t)k * N + n]);
}

// WaT [n=128][k=128] bf16: n<64 -> Wa[k][n] (top half), n>=64 -> Wa[128+k][n-64] (bottom half)
__global__ void build_wa_kernel(const float* __restrict__ Wa, unsigned short* __restrict__ WaT){
  int i = blockIdx.x * 256 + threadIdx.x;
  if (i >= 128 * 128) return;
  int n = i >> 7, k = i & 127;
  float v = (n < 64) ? Wa[(size_t)k * AH + n] : Wa[(size_t)(128 + k) * AH + (n - 64)];
  WaT[i] = f2bf(v);
}

// ---------------- bf16 MFMA GEMM:  C = A[M,K] x BT[N,K]^T ----------------
// OP: 0 relu->bf16   1 +bias -> f32 + bf16   2 -> bf16   3 -> f32
template<int OP>
__global__ __launch_bounds__(256) void gemm_bt(
    const unsigned short* __restrict__ A, const unsigned short* __restrict__ BT,
    float* __restrict__ Cf, unsigned short* __restrict__ Cb,
    const float* __restrict__ bias,
    int M, int N, int K, long long Abatch, long long Cbatch)
{
  __shared__ unsigned short As[128 * 32];
  __shared__ unsigned short Bs[128 * 32];
  const int tid = threadIdx.x;
  const int wave = tid >> 6, lane = tid & 63;
  A += (size_t)blockIdx.z * Abatch;
  const size_t coff = (size_t)blockIdx.z * Cbatch;
  const int row0 = blockIdx.x * 128, col0 = blockIdx.y * 128;
  const int wr = (wave >> 1) * 64, wc = (wave & 1) * 64;
  f32x4 acc[4][4];
  #pragma unroll
  for (int m = 0; m < 4; m++)
    #pragma unroll
    for (int n = 0; n < 4; n++) acc[m][n] = (f32x4){0.f, 0.f, 0.f, 0.f};
  const int lrow = lane >> 2, lk = (lane & 3) * 8;

  for (int k0 = 0; k0 < K; k0 += 32){
    __syncthreads();
    #pragma unroll
    for (int j = 0; j < 2; j++){
      const int rb = (wave * 2 + j) * 16;       // wave-uniform LDS base row
      const int ra = rb + lrow;
      int gr = row0 + ra; gr = gr < M ? gr : M - 1;
      g2l16(A + (size_t)gr * K + k0 + lk, As + rb * 32);
      int gc = col0 + ra; gc = gc < N ? gc : N - 1;
      g2l16(BT + (size_t)gc * K + k0 + lk, Bs + rb * 32);
    }
    __syncthreads();
    bf16x8 af[4], bfr[4];
    #pragma unroll
    for (int m = 0; m < 4; m++)
      af[m] = *reinterpret_cast<const bf16x8*>(&As[(wr + m * 16 + (lane & 15)) * 32 + (lane >> 4) * 8]);
    #pragma unroll
    for (int n = 0; n < 4; n++)
      bfr[n] = *reinterpret_cast<const bf16x8*>(&Bs[(wc + n * 16 + (lane & 15)) * 32 + (lane >> 4) * 8]);
    #pragma unroll
    for (int m = 0; m < 4; m++)
      #pragma unroll
      for (int n = 0; n < 4; n++)
        acc[m][n] = __builtin_amdgcn_mfma_f32_16x16x32_bf16(af[m], bfr[n], acc[m][n], 0, 0, 0);
  }

  const int rbase = row0 + wr + (lane >> 4) * 4;
  const int cbase = col0 + wc + (lane & 15);
  #pragma unroll
  for (int m = 0; m < 4; m++){
    #pragma unroll
    for (int n = 0; n < 4; n++){
      const int col = cbase + n * 16;
      #pragma unroll
      for (int i = 0; i < 4; i++){
        const int row = rbase + m * 16 + i;
        if (row < M){
          float v = acc[m][n][i];
          if (OP == 0){ v = v > 0.f ? v : 0.f; Cb[coff + (size_t)row * N + col] = f2bf(v); }
          else if (OP == 1){ v += bias[col]; Cf[(size_t)row * N + col] = v; Cb[(size_t)row * N + col] = f2bf(v); }
          else if (OP == 2){ Cb[coff + (size_t)row * N + col] = f2bf(v); }
          else            { Cf[coff + (size_t)row * N + col] = v; }
        }
      }
    }
  }
}

// ---------------- CSR build ----------------

__global__ void hist_kernel(const int* __restrict__ adji, int* __restrict__ counts){
  int e = blockIdx.x * 256 + threadIdx.x;
  int h = blockIdx.y;
  if (e >= NE) return;
  int r = adji[(size_t)h * 2 * NE + e];
  atomicAdd(&counts[h * NA + r], 1);
}

__global__ __launch_bounds__(1024) void scan1_kernel(const int* __restrict__ counts,
                                                     int* __restrict__ offs, int* __restrict__ bsums, int n){
  __shared__ int tmp[1024];
  int tid = threadIdx.x, i = blockIdx.x * 1024 + tid;
  int v = (i < n) ? counts[i] : 0;
  tmp[tid] = v; __syncthreads();
  for (int o = 1; o < 1024; o <<= 1){
    int t = (tid >= o) ? tmp[tid - o] : 0;
    __syncthreads();
    tmp[tid] += t;
    __syncthreads();
  }
  if (i < n) offs[i] = tmp[tid] - v;            // exclusive
  if (tid == 1023) bsums[blockIdx.x] = tmp[1023];
}

__global__ void scan2_kernel(int* __restrict__ bsums, int nb){
  __shared__ int tmp[256];
  int tid = threadIdx.x;
  int v = (tid < nb) ? bsums[tid] : 0;
  tmp[tid] = v; __syncthreads();
  for (int o = 1; o < 256; o <<= 1){
    int t = (tid >= o) ? tmp[tid - o] : 0;
    __syncthreads();
    tmp[tid] += t;
    __syncthreads();
  }
  if (tid < nb) bsums[tid] = tmp[tid] - v;      // exclusive block offsets
}

__global__ __launch_bounds__(1024) void scan3_kernel(int* __restrict__ offs, const int* __restrict__ bsums,
                                                     int n, int total){
  int i = blockIdx.x * 1024 + threadIdx.x;
  if (i < n) offs[i] += bsums[i >> 10];
  if (i == 0) offs[n] = total;
}

__global__ void scatter_kernel(const int* __restrict__ adji, const int* __restrict__ offs,
                               int* __restrict__ c2, int* __restrict__ eids){
  int e = blockIdx.x * 256 + threadIdx.x;
  int h = blockIdx.y;
  if (e >= NE) return;
  int r = adji[(size_t)h * 2 * NE + e];
  int p = atomicAdd(&c2[h * NA + r], 1);
  eids[offs[h * NA + r] + p] = e;
}

// agg[h][r][c] = sum_e v_e * z[col_e][c]   (gather form, no float atomics)
__global__ __launch_bounds__(128) void gather_kernel(
    const int* __restrict__ offs, const int* __restrict__ eids,
    const float* __restrict__ adjv, const int* __restrict__ adji,
    const unsigned short* __restrict__ zbf, unsigned short* __restrict__ aggbf)
{
  __shared__ float s_val[128];
  __shared__ int   s_col[128];
  int r = blockIdx.x, h = blockIdx.y, c = threadIdx.x;
  int base = h * NA + r;
  int s = offs[base], e = offs[base + 1];
  const float* vals = adjv + (size_t)h * NE;
  const int*   cols = adji + (size_t)h * 2 * NE + NE;
  float acc = 0.f;
  for (int p0 = s; p0 < e; p0 += 128){
    int cnt = min(128, e - p0);
    __syncthreads();
    if (c < cnt){ int eid = eids[p0 + c]; s_val[c] = vals[eid]; s_col[c] = cols[eid]; }
    __syncthreads();
    for (int q = 0; q < cnt; q++)
      acc += s_val[q] * bf2f(zbf[(size_t)s_col[q] * NC + c]);
  }
  aggbf[(size_t)base * NC + c] = f2bf(acc);
}

// ---------------- fused attention epilogue ----------------
// one wave per node; scores from precomputed ZW (=z@[Wa_top|Wa_bot], f32) and EW (=emb@[..], bf16, use cols 64..127)
__global__ __launch_bounds__(256) void final_kernel(
    const float* __restrict__ z, const unsigned short* __restrict__ embs,
    const float* __restrict__ ZW, const unsigned short* __restrict__ EW,
    const float* __restrict__ ba, const float* __restrict__ va,
    const int* __restrict__ idx, float* __restrict__ out)
{
  int tid = threadIdx.x, wave = tid >> 6, lane = tid & 63;
  int n = blockIdx.x * 4 + wave;
  if (n >= NA) return;
  int an = idx[n];
  float qa = ZW[(size_t)an * NC + lane] + ba[lane];
  float vaj = va[lane];
  float sc[5];
  {
    float s0 = ZW[(size_t)an * NC + 64 + lane];
    float t = tanh_fast(qa + s0) * vaj;
    #pragma unroll
    for (int o = 32; o; o >>= 1) t += __shfl_xor(t, o);
    sc[0] = t;
  }
  #pragma unroll
  for (int h = 1; h < 5; h++){
    float sh = bf2f(EW[((size_t)(h - 1) * NA + n) * NC + 64 + lane]);
    float t = tanh_fast(qa + sh) * vaj;
    #pragma unroll
    for (int o = 32; o; o >>= 1) t += __shfl_xor(t, o);
    sc[h] = t;
  }
  float m = sc[0];
  #pragma unroll
  for (int h = 1; h < 5; h++) m = fmaxf(m, sc[h]);
  float al[5], den = 0.f;
  #pragma unroll
  for (int h = 0; h < 5; h++){ al[h] = __expf(sc[h] - m); den += al[h]; }
  float inv = 1.f / den;
  float o0 = al[0] * z[(size_t)an * NC + lane];
  float o1 = al[0] * z[(size_t)an * NC + 64 + lane];
  #pragma unroll
  for (int h = 1; h < 5; h++){
    o0 += al[h] * bf2f(embs[((size_t)(h - 1) * NA + n) * NC + lane]);
    o1 += al[h] * bf2f(embs[((size_t)(h - 1) * NA + n) * NC + 64 + lane]);
  }
  o0 *= inv; o1 *= inv;
  float mx = fmaxf(o0, o1);
  #pragma unroll
  for (int o = 32; o; o >>= 1) mx = fmaxf(mx, __shfl_xor(mx, o));
  float se = __expf(o0 - mx) + __expf(o1 - mx);
  #pragma unroll
  for (int o = 32; o; o >>= 1) se += __shfl_xor(se, o);
  float ls = __logf(se);
  out[(size_t)n * NC + lane]      = o0 - mx - ls;
  out[(size_t)n * NC + 64 + lane] = o1 - mx - ls;
}

// ---------------- launch ----------------

extern "C" void kernel_launch(void* const* d_in, const int* in_sizes, int n_in,
                              void* d_out, int out_size, void* d_ws, size_t ws_size,
                              hipStream_t stream)
{
  const float* x    = (const float*)d_in[0];
  const float* W1   = (const float*)d_in[1];
  const float* W2   = (const float*)d_in[2];
  const float* b2   = (const float*)d_in[3];
  const float* Wg   = (const float*)d_in[4];
  const float* Wa   = (const float*)d_in[5];
  const float* ba   = (const float*)d_in[6];
  const float* va   = (const float*)d_in[7];
  const float* adjv = (const float*)d_in[8];
  const int*   adji = (const int*)d_in[9];
  const int*   idx  = (const int*)d_in[10];
  float* out = (float*)d_out;
  (void)in_sizes; (void)n_in; (void)out_size; (void)ws_size;

  char* w = (char*)d_ws;
  auto alloc = [&](size_t b) -> char* { char* p = w; w += (b + 255) & ~(size_t)255; return p; };
  unsigned short* Xbf  = (unsigned short*)alloc((size_t)NA * NFEAT * 2);  // 51.2MB; 'embs' aliases after GEMM1 consumes it
  unsigned short* Hbuf = (unsigned short*)alloc((size_t)NA * HID * 2);    // 51.2MB; 'aggbf' then 'EW' alias
  unsigned short* W1T  = (unsigned short*)alloc((size_t)HID * NFEAT * 2);
  unsigned short* W2T  = (unsigned short*)alloc((size_t)NC * HID * 2);
  unsigned short* WgT  = (unsigned short*)alloc((size_t)NC * NC * 2);
  unsigned short* WaT  = (unsigned short*)alloc((size_t)NC * NC * 2);
  float*          z    = (float*)alloc((size_t)NA * NC * 4);
  unsigned short* zbf  = (unsigned short*)alloc((size_t)NA * NC * 2);
  float*          ZW   = (float*)alloc((size_t)NA * NC * 4);
  int* counts = (int*)alloc((size_t)NHOP * NA * 4);
  int* c2     = (int*)alloc((size_t)NHOP * NA * 4);
  int* offs   = (int*)alloc(((size_t)NHOP * NA + 1) * 4);
  int* bsums  = (int*)alloc(256 * 4);
  int* eids   = (int*)alloc((size_t)NHOP * NE * 4);
  unsigned short* embs  = Xbf;   // [4][NA][NC] bf16
  unsigned short* aggbf = Hbuf;  // [4][NA][NC] bf16
  unsigned short* EW    = Hbuf;  // [4][NA][NC] bf16 (overwrites aggbf after hop GEMM)

  // casts / weight transposes
  cast_x_kernel<<<dim3((NA * NFEAT / 4 + 255) / 256), 256, 0, stream>>>(x, Xbf, NA * NFEAT / 4);
  transpose_cast_kernel<<<dim3((NFEAT * HID + 255) / 256), 256, 0, stream>>>(W1, W1T, NFEAT, HID);
  transpose_cast_kernel<<<dim3((HID * NC + 255) / 256), 256, 0, stream>>>(W2, W2T, HID, NC);
  transpose_cast_kernel<<<dim3((NC * NC + 255) / 256), 256, 0, stream>>>(Wg, WgT, NC, NC);
  build_wa_kernel<<<dim3(64), 256, 0, stream>>>(Wa, WaT);

  // z = relu(x@W1)@W2 + b2
  gemm_bt<0><<<dim3(391, 4, 1), 256, 0, stream>>>(Xbf, W1T, nullptr, Hbuf, nullptr, NA, HID, NFEAT, 0, 0);
  gemm_bt<1><<<dim3(391, 1, 1), 256, 0, stream>>>(Hbuf, W2T, z, zbf, b2, NA, NC, HID, 0, 0);

  // CSR build (all hops batched)
  hipMemsetAsync(counts, 0, (size_t)NHOP * NA * 4, stream);
  hipMemsetAsync(c2,     0, (size_t)NHOP * NA * 4, stream);
  hist_kernel<<<dim3(NE / 256, NHOP), 256, 0, stream>>>(adji, counts);
  scan1_kernel<<<dim3((NHOP * NA + 1023) / 1024), 1024, 0, stream>>>(counts, offs, bsums, NHOP * NA);
  scan2_kernel<<<dim3(1), 256, 0, stream>>>(bsums, (NHOP * NA + 1023) / 1024);
  scan3_kernel<<<dim3((NHOP * NA + 1023) / 1024), 1024, 0, stream>>>(offs, bsums, NHOP * NA, NHOP * NE);
  scatter_kernel<<<dim3(NE / 256, NHOP), 256, 0, stream>>>(adji, offs, c2, eids);

  // aggregate + hop GEMMs (batched over 4 hops)
  gather_kernel<<<dim3(NA, NHOP), 128, 0, stream>>>(offs, eids, adjv, adji, zbf, aggbf);
  gemm_bt<2><<<dim3(391, 1, NHOP), 256, 0, stream>>>(aggbf, WgT, nullptr, embs, nullptr,
                                                     NA, NC, NC, (long long)NA * NC, (long long)NA * NC);
  // attention score GEMMs: ZW = z@[Wa_top|Wa_bot] (f32), EW_h = emb_h@[..] (bf16, cols 64..127 used)
  gemm_bt<3><<<dim3(391, 1, 1), 256, 0, stream>>>(zbf, WaT, ZW, nullptr, nullptr, NA, NC, NC, 0, 0);
  gemm_bt<2><<<dim3(391, 1, NHOP), 256, 0, stream>>>(embs, WaT, nullptr, EW, nullptr,
                                                     NA, NC, NC, (long long)NA * NC, (long long)NA * NC);

  // fused softmax-attention + log_softmax
  final_kernel<<<dim3(NA / 4), 256, 0, stream>>>(z, embs, ZW, EW, ba, va, idx, out);
}